// Round 1
// baseline (147.172 us; speedup 1.0000x reference)
//
#include <hip/hip_runtime.h>

#define EPS_LN 1e-5f

constexpr int E = 384;      // input embedding dim
constexpr int H = 256;      // hidden dim
constexpr int NROWS = 8;    // rows per block in path kernel
constexpr int NTHREADS = 256;

struct Params {
  const int* uid;
  const float* qe;
  const float* le;
  const float* tab;
  const float *Wu0,*bu0,*Wq0,*bq0,*Wl0,*bl0,*g0,*be0;
  const float *Wu1,*bu1,*Wq1,*bq1,*Wl1,*bl1,*g1,*be1;
  const float *w1,*b1,*w2,*b2;
  float *lw, *uqw, *out;
};

// 256 threads: tc = tid&63 (4 output cols each), tr = tid>>6 (2 rows each).
// Computes acc[m][n] = sum_k xin[(tr*2+m)*K + k] * W[k*H + tc*4+n]
template<int K>
__device__ __forceinline__ void gemm8(const float* __restrict__ xin,
                                      const float* __restrict__ W,
                                      int tc, int tr, float acc[2][4]) {
  #pragma unroll
  for (int m = 0; m < 2; ++m)
    #pragma unroll
    for (int n = 0; n < 4; ++n) acc[m][n] = 0.f;
  const float* wp = W + tc * 4;
  #pragma unroll 4
  for (int k = 0; k < K; k += 2) {
    float4 w0 = *(const float4*)(wp + (size_t)k * H);
    float4 w1v = *(const float4*)(wp + (size_t)(k + 1) * H);
    #pragma unroll
    for (int m = 0; m < 2; ++m) {
      float2 x = *(const float2*)(xin + (tr * 2 + m) * K + k);
      acc[m][0] += x.x * w0.x; acc[m][0] += x.y * w1v.x;
      acc[m][1] += x.x * w0.y; acc[m][1] += x.y * w1v.y;
      acc[m][2] += x.x * w0.z; acc[m][2] += x.y * w1v.z;
      acc[m][3] += x.x * w0.w; acc[m][3] += x.y * w1v.w;
    }
  }
}

// LayerNorm over H=256 values per row; z held 2 rows x 4 cols per thread.
// out[r][c] = g[c]*(z-mu)*rstd + be[c] (+ addb[r][c] if addb != null)
__device__ __forceinline__ void ln8(float z[2][4], int tc, int tr,
                                    const float* __restrict__ g,
                                    const float* __restrict__ be,
                                    float* red, float* mb, float* rb,
                                    float* outb, const float* addb) {
  #pragma unroll
  for (int m = 0; m < 2; ++m) {
    *(float4*)(red + (tr * 2 + m) * H + tc * 4) =
        make_float4(z[m][0], z[m][1], z[m][2], z[m][3]);
  }
  __syncthreads();
  // wave tr reduces rows {tr, tr+4}
  #pragma unroll
  for (int rr = 0; rr < 2; ++rr) {
    int r = tr + rr * 4;
    const float* row = red + r * H;
    float v0 = row[tc], v1 = row[tc + 64], v2 = row[tc + 128], v3 = row[tc + 192];
    float s1 = v0 + v1 + v2 + v3;
    float s2 = v0 * v0 + v1 * v1 + v2 * v2 + v3 * v3;
    #pragma unroll
    for (int off = 32; off; off >>= 1) {
      s1 += __shfl_xor(s1, off, 64);
      s2 += __shfl_xor(s2, off, 64);
    }
    if (tc == 0) {
      float mu = s1 * (1.f / 256.f);
      float var = s2 * (1.f / 256.f) - mu * mu;
      mb[r] = mu;
      rb[r] = 1.f / sqrtf(var + EPS_LN);
    }
  }
  __syncthreads();
  float4 gv = *(const float4*)(g + tc * 4);
  float4 bev = *(const float4*)(be + tc * 4);
  #pragma unroll
  for (int m = 0; m < 2; ++m) {
    int r = tr * 2 + m;
    float mu = mb[r], rs = rb[r];
    float y0 = gv.x * (z[m][0] - mu) * rs + bev.x;
    float y1 = gv.y * (z[m][1] - mu) * rs + bev.y;
    float y2 = gv.z * (z[m][2] - mu) * rs + bev.z;
    float y3 = gv.w * (z[m][3] - mu) * rs + bev.w;
    if (addb) {
      float4 a = *(const float4*)(addb + r * H + tc * 4);
      y0 += a.x; y1 += a.y; y2 += a.z; y3 += a.w;
    }
    *(float4*)(outb + r * H + tc * 4) = make_float4(y0, y1, y2, y3);
  }
  __syncthreads();
}

// out = LN(2*(xin@W + b)) (+ addb)
template<int K>
__device__ __forceinline__ void chain(const float* xin, const float* W,
                                      const float* b, const float* g,
                                      const float* be, int tc, int tr,
                                      float* red, float* mb, float* rb,
                                      float* outb, const float* addb) {
  float acc[2][4];
  gemm8<K>(xin, W, tc, tr, acc);
  float4 bv = *(const float4*)(b + tc * 4);
  float z[2][4];
  #pragma unroll
  for (int m = 0; m < 2; ++m) {
    z[m][0] = 2.f * (acc[m][0] + bv.x);
    z[m][1] = 2.f * (acc[m][1] + bv.y);
    z[m][2] = 2.f * (acc[m][2] + bv.z);
    z[m][3] = 2.f * (acc[m][3] + bv.w);
  }
  ln8(z, tc, tr, g, be, red, mb, rb, outb, addb);
}

// blocks 0..511: u/q path (8 batch rows each) -> uqw
// blocks 512..519: llm path (8 rows each) -> lw (b1 folded in)
__global__ __launch_bounds__(NTHREADS)
void path_kernel(Params p) {
  __shared__ float xin[NROWS * E];
  __shared__ float bufA[NROWS * H];
  __shared__ float bufB[NROWS * H];
  __shared__ float red[NROWS * H];
  __shared__ float mb[NROWS], rb[NROWS];
  const int tid = threadIdx.x;
  const int tc = tid & 63;
  const int tr = tid >> 6;
  const int bx = blockIdx.x;

  if (bx < 512) {
    const int base = bx * NROWS;
    // gather user embeddings
    for (int r = 0; r < NROWS; ++r) {
      const int u = p.uid[base + r];
      const float* src = p.tab + (size_t)u * E;
      for (int c = tid; c < E; c += NTHREADS) xin[r * E + c] = src[c];
    }
    __syncthreads();
    chain<E>(xin, p.Wu0, p.bu0, p.g0, p.be0, tc, tr, red, mb, rb, bufA, nullptr);
    chain<H>(bufA, p.Wu1, p.bu1, p.g1, p.be1, tc, tr, red, mb, rb, bufB, nullptr);
    // q path (xin free after first chain's gemm reads, barriers inside)
    const float* qs = p.qe + (size_t)base * E;
    for (int i = tid; i < NROWS * E; i += NTHREADS) xin[i] = qs[i];
    __syncthreads();
    chain<E>(xin, p.Wq0, p.bq0, p.g0, p.be0, tc, tr, red, mb, rb, bufA, nullptr);
    // q1 + u1 -> uq (into bufA; safe: gemm reads of bufA precede ln's barriers)
    chain<H>(bufA, p.Wq1, p.bq1, p.g1, p.be1, tc, tr, red, mb, rb, bufA, bufB);
    // uqw = uq @ w1[H:, :]
    float acc[2][4];
    gemm8<H>(bufA, p.w1 + (size_t)H * H, tc, tr, acc);
    #pragma unroll
    for (int m = 0; m < 2; ++m) {
      float* o = p.uqw + (size_t)(base + tr * 2 + m) * H + tc * 4;
      *(float4*)o = make_float4(acc[m][0], acc[m][1], acc[m][2], acc[m][3]);
    }
  } else {
    const int base = (bx - 512) * NROWS;
    const float* ls = p.le + (size_t)base * E;
    for (int i = tid; i < NROWS * E; i += NTHREADS) xin[i] = ls[i];
    __syncthreads();
    chain<E>(xin, p.Wl0, p.bl0, p.g0, p.be0, tc, tr, red, mb, rb, bufA, nullptr);
    chain<H>(bufA, p.Wl1, p.bl1, p.g1, p.be1, tc, tr, red, mb, rb, bufB, nullptr);
    // lw = l1 @ w1[:H, :] + b1
    float acc[2][4];
    gemm8<H>(bufB, p.w1, tc, tr, acc);
    float4 b1v = *(const float4*)(p.b1 + tc * 4);
    #pragma unroll
    for (int m = 0; m < 2; ++m) {
      float* o = p.lw + (size_t)(base + tr * 2 + m) * H + tc * 4;
      *(float4*)o = make_float4(acc[m][0] + b1v.x, acc[m][1] + b1v.y,
                                acc[m][2] + b1v.z, acc[m][3] + b1v.w);
    }
  }
}

// scores[b,l] = sum_j relu(lw[l,j] + uqw[b,j]) * w2[j] + b2
// 1 wave per b; lane = l. lw staged in LDS with pad 257 -> bank (l+j)%32, 2-way free.
__global__ __launch_bounds__(256)
void score_kernel(const float* __restrict__ lw, const float* __restrict__ uqw,
                  const float* __restrict__ w2, const float* __restrict__ b2,
                  float* __restrict__ out) {
  __shared__ float lw_s[64 * 257];
  __shared__ float w2_s[256];
  __shared__ float uq_s[4 * 256];
  const int tid = threadIdx.x;
  for (int i = tid; i < 64 * 256; i += 256) {
    int r = i >> 8, c = i & 255;
    lw_s[r * 257 + c] = lw[i];
  }
  w2_s[tid] = w2[tid];
  const int w = tid >> 6, lane = tid & 63;
  const int b = blockIdx.x * 4 + w;
  *(float4*)(uq_s + w * 256 + lane * 4) =
      *(const float4*)(uqw + (size_t)b * 256 + lane * 4);
  __syncthreads();
  const float* lrow = lw_s + lane * 257;
  const float* urow = uq_s + w * 256;
  float acc = 0.f;
  #pragma unroll 8
  for (int j = 0; j < 256; ++j) {
    float v = lrow[j] + urow[j];
    acc += fmaxf(v, 0.f) * w2_s[j];
  }
  out[(size_t)b * 64 + lane] = acc + b2[0];
}

extern "C" void kernel_launch(void* const* d_in, const int* in_sizes, int n_in,
                              void* d_out, int out_size, void* d_ws, size_t ws_size,
                              hipStream_t stream) {
  (void)in_sizes; (void)n_in; (void)out_size; (void)ws_size;
  Params p;
  p.uid = (const int*)d_in[0];
  p.qe  = (const float*)d_in[1];
  p.le  = (const float*)d_in[2];
  p.tab = (const float*)d_in[3];
  p.Wu0 = (const float*)d_in[4];  p.bu0 = (const float*)d_in[5];
  p.Wq0 = (const float*)d_in[6];  p.bq0 = (const float*)d_in[7];
  p.Wl0 = (const float*)d_in[8];  p.bl0 = (const float*)d_in[9];
  p.g0  = (const float*)d_in[10]; p.be0 = (const float*)d_in[11];
  p.Wu1 = (const float*)d_in[12]; p.bu1 = (const float*)d_in[13];
  p.Wq1 = (const float*)d_in[14]; p.bq1 = (const float*)d_in[15];
  p.Wl1 = (const float*)d_in[16]; p.be1 = (const float*)d_in[17];
  p.Wl1 = (const float*)d_in[16]; p.bl1 = (const float*)d_in[17];
  p.g1  = (const float*)d_in[18]; p.be1 = (const float*)d_in[19];
  p.w1  = (const float*)d_in[20]; p.b1  = (const float*)d_in[21];
  p.w2  = (const float*)d_in[22]; p.b2  = (const float*)d_in[23];
  float* ws = (float*)d_ws;
  p.lw  = ws;                 // 64*256 floats
  p.uqw = ws + 64 * 256;      // 4096*256 floats
  p.out = (float*)d_out;
  hipLaunchKernelGGL(path_kernel, dim3(520), dim3(NTHREADS), 0, stream, p);
  hipLaunchKernelGGL(score_kernel, dim3(1024), dim3(256), 0, stream,
                     p.lw, p.uqw, p.w2, p.b2, p.out);
}

// Round 2
// 80.198 us; speedup vs baseline: 1.8351x; 1.8351x over previous
//
#include <hip/hip_runtime.h>

constexpr int E = 384;
constexpr int H = 256;
#define EPS_LN 1e-5f

using f32x4 = __attribute__((ext_vector_type(4))) float;
using s16x8 = __attribute__((ext_vector_type(8))) short;

__device__ __forceinline__ short f2bf(float f) {
  union { float f; unsigned u; } v; v.f = f;
  unsigned r = v.u + 0x7fff + ((v.u >> 16) & 1);
  return (short)(r >> 16);
}

__device__ __forceinline__ s16x8 cvt8(const float4 a, const float4 b) {
  s16x8 r;
  r[0] = f2bf(a.x); r[1] = f2bf(a.y); r[2] = f2bf(a.z); r[3] = f2bf(a.w);
  r[4] = f2bf(b.x); r[5] = f2bf(b.y); r[6] = f2bf(b.z); r[7] = f2bf(b.w);
  return r;
}

#define MFMA(a, b, c) __builtin_amdgcn_mfma_f32_16x16x32_bf16((a), (b), (c), 0, 0, 0)

struct P {
  const int* uid;
  const float *qe, *le, *tab;
  const float *Wu0, *bu0, *Wq0, *bq0, *Wl0, *bl0, *g0, *be0;
  const float *Wu1, *bu1, *Wq1, *bq1, *Wl1, *bl1, *g1, *be1;
  const float *w1, *b1, *w2, *b2;
  short *wt0u, *wt0q, *wt0l, *wt1u, *wt1q, *wt1l, *w1t;  // bf16 transposed weights
  short *y0, *uqL, *l1;                                  // bf16 activations
  float *uqw, *lw, *out;
};

// ---- prep: cast + transpose weights to bf16, Wt[n][k] = W[k][n] ----
__global__ __launch_bounds__(256) void prep_kernel(P p) {
  const int idx = blockIdx.x * 256 + threadIdx.x;
  const int S0 = 384 * 256, S1 = 256 * 256;
  if (idx < 3 * S0) {
    int m = idx / S0, r = idx - m * S0;
    int k = r >> 8, n = r & 255;
    const float* W = (m == 0) ? p.Wu0 : (m == 1) ? p.Wq0 : p.Wl0;
    short* T = (m == 0) ? p.wt0u : (m == 1) ? p.wt0q : p.wt0l;
    T[n * 384 + k] = f2bf(W[r]);
  } else if (idx < 3 * S0 + 3 * S1) {
    int j = idx - 3 * S0;
    int m = j / S1, r = j - m * S1;
    int k = r >> 8, n = r & 255;
    const float* W = (m == 0) ? p.Wu1 : (m == 1) ? p.Wq1 : p.Wl1;
    short* T = (m == 0) ? p.wt1u : (m == 1) ? p.wt1q : p.wt1l;
    T[n * 256 + k] = f2bf(W[r]);
  } else {
    int r = idx - 3 * S0 - 3 * S1;  // < 512*256
    int k = r >> 8, n = r & 255;
    p.w1t[n * 512 + k] = f2bf(p.w1[r]);
  }
}

// ---- G0: gather + GEMM(E->H) + LN -> y0 bf16 [8256][256] ----
// grid 516 blocks x 256 thr; block = 16 rows x 256 cols; wave w = cols w*64..
__global__ __launch_bounds__(256) void g0_kernel(P p) {
  __shared__ float ssum[4][16], ssq[4][16], mub[16], rsb[16];
  const int tid = threadIdx.x, w = tid >> 6, l = tid & 63;
  const int lr = l & 15, lg = l >> 4;
  const int t = blockIdx.x;
  const int r0 = t * 16;
  const int row = r0 + lr;
  const float* src;
  const short* wt;
  const float* bias;
  if (t < 256)      { src = p.tab + (size_t)p.uid[row] * E; wt = p.wt0u; bias = p.bu0; }
  else if (t < 512) { src = p.qe + (size_t)(row - 4096) * E; wt = p.wt0q; bias = p.bq0; }
  else              { src = p.le + (size_t)(row - 8192) * E; wt = p.wt0l; bias = p.bl0; }
  const int c0 = w * 64, ka = lg * 8;
  const float4* ap4 = (const float4*)(src + ka);
  const s16x8* wp[4];
  #pragma unroll
  for (int n = 0; n < 4; ++n)
    wp[n] = (const s16x8*)(wt + (size_t)(c0 + n * 16 + lr) * 384 + ka);
  f32x4 acc[4];
  const f32x4 z4 = {0.f, 0.f, 0.f, 0.f};
  #pragma unroll
  for (int n = 0; n < 4; ++n) acc[n] = z4;
  #pragma unroll 4
  for (int kk = 0; kk < 12; ++kk) {
    s16x8 a = cvt8(ap4[kk * 8], ap4[kk * 8 + 1]);
    #pragma unroll
    for (int n = 0; n < 4; ++n) acc[n] = MFMA(a, wp[n][kk * 4], acc[n]);
  }
  // epilogue: z = 2*(acc + bias); LN over the 256 cols of each row
  float z[4][4];
  float s1[4] = {0, 0, 0, 0}, s2[4] = {0, 0, 0, 0};
  #pragma unroll
  for (int n = 0; n < 4; ++n) {
    const float bv = bias[c0 + n * 16 + lr];
    #pragma unroll
    for (int r = 0; r < 4; ++r) {
      float zz = 2.f * (acc[n][r] + bv);
      z[n][r] = zz;
      s1[r] += zz;
      s2[r] += zz * zz;
    }
  }
  #pragma unroll
  for (int off = 1; off < 16; off <<= 1) {
    #pragma unroll
    for (int r = 0; r < 4; ++r) {
      s1[r] += __shfl_xor(s1[r], off, 64);
      s2[r] += __shfl_xor(s2[r], off, 64);
    }
  }
  if (lr == 0) {
    #pragma unroll
    for (int r = 0; r < 4; ++r) { ssum[w][lg * 4 + r] = s1[r]; ssq[w][lg * 4 + r] = s2[r]; }
  }
  __syncthreads();
  if (tid < 16) {
    float S1 = 0, S2 = 0;
    #pragma unroll
    for (int ww = 0; ww < 4; ++ww) { S1 += ssum[ww][tid]; S2 += ssq[ww][tid]; }
    float mu = S1 * (1.f / 256.f);
    float var = S2 * (1.f / 256.f) - mu * mu;
    mub[tid] = mu;
    rsb[tid] = rsqrtf(var + EPS_LN);
  }
  __syncthreads();
  #pragma unroll
  for (int n = 0; n < 4; ++n) {
    const int c = c0 + n * 16 + lr;
    const float gv = p.g0[c], bev = p.be0[c];
    #pragma unroll
    for (int r = 0; r < 4; ++r) {
      const int rr = lg * 4 + r;
      float y = gv * (z[n][r] - mub[rr]) * rsb[rr] + bev;
      p.y0[(size_t)(r0 + rr) * 256 + c] = f2bf(y);
    }
  }
}

// ---- G1: layer1 GEMM(H->H) + LN; u/q fused with add -> uqL; l -> l1 ----
// grid 260 blocks x 256 thr (0..255: u&q rows 16*t; 256..259: l rows)
__global__ __launch_bounds__(256) void g1_kernel(P p) {
  __shared__ float ssum[2][4][16], ssq[2][4][16], mub[2][16], rsb[2][16];
  const int tid = threadIdx.x, w = tid >> 6, l = tid & 63;
  const int lr = l & 15, lg = l >> 4;
  const int t = blockIdx.x;
  const int c0 = w * 64, ka = lg * 8;
  const f32x4 z4 = {0.f, 0.f, 0.f, 0.f};
  if (t < 256) {
    const int r0 = t * 16;
    const s16x8* apU = (const s16x8*)(p.y0 + (size_t)(r0 + lr) * 256 + ka);
    const s16x8* apQ = (const s16x8*)(p.y0 + (size_t)(4096 + r0 + lr) * 256 + ka);
    const s16x8 *wpU[4], *wpQ[4];
    #pragma unroll
    for (int n = 0; n < 4; ++n) {
      wpU[n] = (const s16x8*)(p.wt1u + (size_t)(c0 + n * 16 + lr) * 256 + ka);
      wpQ[n] = (const s16x8*)(p.wt1q + (size_t)(c0 + n * 16 + lr) * 256 + ka);
    }
    f32x4 aU[4], aQ[4];
    #pragma unroll
    for (int n = 0; n < 4; ++n) { aU[n] = z4; aQ[n] = z4; }
    #pragma unroll 2
    for (int kk = 0; kk < 8; ++kk) {
      s16x8 xu = apU[kk * 4], xq = apQ[kk * 4];
      #pragma unroll
      for (int n = 0; n < 4; ++n) {
        aU[n] = MFMA(xu, wpU[n][kk * 4], aU[n]);
        aQ[n] = MFMA(xq, wpQ[n][kk * 4], aQ[n]);
      }
    }
    float zU[4][4], zQ[4][4];
    float s1[2][4] = {{0}}, s2[2][4] = {{0}};
    #pragma unroll
    for (int n = 0; n < 4; ++n) {
      const int c = c0 + n * 16 + lr;
      const float bU = p.bu1[c], bQ = p.bq1[c];
      #pragma unroll
      for (int r = 0; r < 4; ++r) {
        float vu = 2.f * (aU[n][r] + bU);
        float vq = 2.f * (aQ[n][r] + bQ);
        zU[n][r] = vu; zQ[n][r] = vq;
        s1[0][r] += vu; s2[0][r] += vu * vu;
        s1[1][r] += vq; s2[1][r] += vq * vq;
      }
    }
    #pragma unroll
    for (int off = 1; off < 16; off <<= 1) {
      #pragma unroll
      for (int ch = 0; ch < 2; ++ch)
        #pragma unroll
        for (int r = 0; r < 4; ++r) {
          s1[ch][r] += __shfl_xor(s1[ch][r], off, 64);
          s2[ch][r] += __shfl_xor(s2[ch][r], off, 64);
        }
    }
    if (lr == 0) {
      #pragma unroll
      for (int ch = 0; ch < 2; ++ch)
        #pragma unroll
        for (int r = 0; r < 4; ++r) {
          ssum[ch][w][lg * 4 + r] = s1[ch][r];
          ssq[ch][w][lg * 4 + r] = s2[ch][r];
        }
    }
    __syncthreads();
    if (tid < 32) {
      const int ch = tid >> 4, rr = tid & 15;
      float S1 = 0, S2 = 0;
      #pragma unroll
      for (int ww = 0; ww < 4; ++ww) { S1 += ssum[ch][ww][rr]; S2 += ssq[ch][ww][rr]; }
      float mu = S1 * (1.f / 256.f);
      float var = S2 * (1.f / 256.f) - mu * mu;
      mub[ch][rr] = mu;
      rsb[ch][rr] = rsqrtf(var + EPS_LN);
    }
    __syncthreads();
    #pragma unroll
    for (int n = 0; n < 4; ++n) {
      const int c = c0 + n * 16 + lr;
      const float gv = p.g1[c], bev = p.be1[c];
      #pragma unroll
      for (int r = 0; r < 4; ++r) {
        const int rr = lg * 4 + r;
        float yu = gv * (zU[n][r] - mub[0][rr]) * rsb[0][rr] + bev;
        float yq = gv * (zQ[n][r] - mub[1][rr]) * rsb[1][rr] + bev;
        p.uqL[(size_t)(r0 + rr) * 256 + c] = f2bf(yu + yq);
      }
    }
  } else {
    const int rt = t - 256;
    const int r0 = rt * 16;
    const s16x8* ap = (const s16x8*)(p.y0 + (size_t)(8192 + r0 + lr) * 256 + ka);
    const s16x8* wp[4];
    #pragma unroll
    for (int n = 0; n < 4; ++n)
      wp[n] = (const s16x8*)(p.wt1l + (size_t)(c0 + n * 16 + lr) * 256 + ka);
    f32x4 acc[4];
    #pragma unroll
    for (int n = 0; n < 4; ++n) acc[n] = z4;
    #pragma unroll 4
    for (int kk = 0; kk < 8; ++kk) {
      s16x8 x = ap[kk * 4];
      #pragma unroll
      for (int n = 0; n < 4; ++n) acc[n] = MFMA(x, wp[n][kk * 4], acc[n]);
    }
    float z[4][4];
    float s1[4] = {0, 0, 0, 0}, s2[4] = {0, 0, 0, 0};
    #pragma unroll
    for (int n = 0; n < 4; ++n) {
      const float bv = p.bl1[c0 + n * 16 + lr];
      #pragma unroll
      for (int r = 0; r < 4; ++r) {
        float zz = 2.f * (acc[n][r] + bv);
        z[n][r] = zz; s1[r] += zz; s2[r] += zz * zz;
      }
    }
    #pragma unroll
    for (int off = 1; off < 16; off <<= 1) {
      #pragma unroll
      for (int r = 0; r < 4; ++r) {
        s1[r] += __shfl_xor(s1[r], off, 64);
        s2[r] += __shfl_xor(s2[r], off, 64);
      }
    }
    if (lr == 0) {
      #pragma unroll
      for (int r = 0; r < 4; ++r) { ssum[0][w][lg * 4 + r] = s1[r]; ssq[0][w][lg * 4 + r] = s2[r]; }
    }
    __syncthreads();
    if (tid < 16) {
      float S1 = 0, S2 = 0;
      #pragma unroll
      for (int ww = 0; ww < 4; ++ww) { S1 += ssum[0][ww][tid]; S2 += ssq[0][ww][tid]; }
      float mu = S1 * (1.f / 256.f);
      float var = S2 * (1.f / 256.f) - mu * mu;
      mub[0][tid] = mu;
      rsb[0][tid] = rsqrtf(var + EPS_LN);
    }
    __syncthreads();
    #pragma unroll
    for (int n = 0; n < 4; ++n) {
      const int c = c0 + n * 16 + lr;
      const float gv = p.g1[c], bev = p.be1[c];
      #pragma unroll
      for (int r = 0; r < 4; ++r) {
        const int rr = lg * 4 + r;
        float y = gv * (z[n][r] - mub[0][rr]) * rsb[0][rr] + bev;
        p.l1[(size_t)(r0 + rr) * 256 + c] = f2bf(y);
      }
    }
  }
}

// ---- G2: uqw = uq @ w1[H:,:] ; lw = l1 @ w1[:H,:] + b1 (fp32 out) ----
// grid 1040 blocks x 64 thr: rt = bx>>2 (260 row tiles), ct = bx&3
__global__ __launch_bounds__(64) void g2_kernel(P p) {
  const int bx = blockIdx.x;
  const int rt = bx >> 2, ct = bx & 3;
  const int l = threadIdx.x, lr = l & 15, lg = l >> 4;
  const int c0 = ct * 64, ka = lg * 8;
  const s16x8* ap;
  const s16x8* wp[4];
  float* outp;
  bool addb;
  int orow;
  if (rt < 256) {
    ap = (const s16x8*)(p.uqL + (size_t)(rt * 16 + lr) * 256 + ka);
    #pragma unroll
    for (int n = 0; n < 4; ++n)
      wp[n] = (const s16x8*)(p.w1t + (size_t)(c0 + n * 16 + lr) * 512 + 256 + ka);
    outp = p.uqw; addb = false; orow = rt * 16;
  } else {
    ap = (const s16x8*)(p.l1 + (size_t)((rt - 256) * 16 + lr) * 256 + ka);
    #pragma unroll
    for (int n = 0; n < 4; ++n)
      wp[n] = (const s16x8*)(p.w1t + (size_t)(c0 + n * 16 + lr) * 512 + ka);
    outp = p.lw; addb = true; orow = (rt - 256) * 16;
  }
  f32x4 acc[4];
  const f32x4 z4 = {0.f, 0.f, 0.f, 0.f};
  #pragma unroll
  for (int n = 0; n < 4; ++n) acc[n] = z4;
  #pragma unroll 4
  for (int kk = 0; kk < 8; ++kk) {
    s16x8 a = ap[kk * 4];
    #pragma unroll
    for (int n = 0; n < 4; ++n) acc[n] = MFMA(a, wp[n][kk * 4], acc[n]);
  }
  #pragma unroll
  for (int n = 0; n < 4; ++n) {
    const int c = c0 + n * 16 + lr;
    const float bv = addb ? p.b1[c] : 0.f;
    #pragma unroll
    for (int r = 0; r < 4; ++r)
      outp[(size_t)(orow + lg * 4 + r) * 256 + c] = acc[n][r] + bv;
  }
}

// ---- score: out[b][l] = sum_j relu(lw[l][j] + uqw[b][j]) * w2[j] + b2 ----
__global__ __launch_bounds__(256) void score_kernel(const float* __restrict__ lw,
                                                    const float* __restrict__ uqw,
                                                    const float* __restrict__ w2,
                                                    const float* __restrict__ b2,
                                                    float* __restrict__ out) {
  __shared__ float lw_s[64 * 257];
  __shared__ float w2_s[256];
  __shared__ float uq_s[4 * 256];
  const int tid = threadIdx.x;
  for (int i = tid; i < 64 * 256; i += 256) {
    int r = i >> 8, c = i & 255;
    lw_s[r * 257 + c] = lw[i];
  }
  w2_s[tid] = w2[tid];
  const int w = tid >> 6, lane = tid & 63;
  const int b = blockIdx.x * 4 + w;
  *(float4*)(uq_s + w * 256 + lane * 4) =
      *(const float4*)(uqw + (size_t)b * 256 + lane * 4);
  __syncthreads();
  const float* lrow = lw_s + lane * 257;
  const float* urow = uq_s + w * 256;
  float acc = 0.f;
  #pragma unroll 8
  for (int j = 0; j < 256; ++j) {
    float v = lrow[j] + urow[j];
    acc += fmaxf(v, 0.f) * w2_s[j];
  }
  out[(size_t)b * 64 + lane] = acc + b2[0];
}

extern "C" void kernel_launch(void* const* d_in, const int* in_sizes, int n_in,
                              void* d_out, int out_size, void* d_ws, size_t ws_size,
                              hipStream_t stream) {
  (void)in_sizes; (void)n_in; (void)out_size; (void)ws_size;
  P p;
  p.uid = (const int*)d_in[0];
  p.qe  = (const float*)d_in[1];
  p.le  = (const float*)d_in[2];
  p.tab = (const float*)d_in[3];
  p.Wu0 = (const float*)d_in[4];  p.bu0 = (const float*)d_in[5];
  p.Wq0 = (const float*)d_in[6];  p.bq0 = (const float*)d_in[7];
  p.Wl0 = (const float*)d_in[8];  p.bl0 = (const float*)d_in[9];
  p.g0  = (const float*)d_in[10]; p.be0 = (const float*)d_in[11];
  p.Wu1 = (const float*)d_in[12]; p.bu1 = (const float*)d_in[13];
  p.Wq1 = (const float*)d_in[14]; p.bq1 = (const float*)d_in[15];
  p.Wl1 = (const float*)d_in[16]; p.bl1 = (const float*)d_in[17];
  p.g1  = (const float*)d_in[18]; p.be1 = (const float*)d_in[19];
  p.w1  = (const float*)d_in[20]; p.b1  = (const float*)d_in[21];
  p.w2  = (const float*)d_in[22]; p.b2  = (const float*)d_in[23];

  short* wsS = (short*)d_ws;
  size_t o = 0;
  p.wt0u = wsS + o; o += 98304;     // 256x384
  p.wt0q = wsS + o; o += 98304;
  p.wt0l = wsS + o; o += 98304;
  p.wt1u = wsS + o; o += 65536;     // 256x256
  p.wt1q = wsS + o; o += 65536;
  p.wt1l = wsS + o; o += 65536;
  p.w1t  = wsS + o; o += 131072;    // 256x512
  p.y0   = wsS + o; o += 2113536;   // 8256x256
  p.uqL  = wsS + o; o += 1048576;   // 4096x256
  p.l1   = wsS + o; o += 16384;     // 64x256
  float* wsF = (float*)(wsS + o);   // byte offset 7602176, 16B aligned
  p.uqw = wsF;                      // 4096x256 fp32
  p.lw  = wsF + 1048576;            // 64x256 fp32
  p.out = (float*)d_out;

  hipLaunchKernelGGL(prep_kernel, dim3(2432), dim3(256), 0, stream, p);
  hipLaunchKernelGGL(g0_kernel, dim3(516), dim3(256), 0, stream, p);
  hipLaunchKernelGGL(g1_kernel, dim3(260), dim3(256), 0, stream, p);
  hipLaunchKernelGGL(g2_kernel, dim3(1040), dim3(64), 0, stream, p);
  hipLaunchKernelGGL(score_kernel, dim3(1024), dim3(256), 0, stream,
                     p.lw, p.uqw, p.w2, p.b2, p.out);
}